// Round 1
// baseline (558.299 us; speedup 1.0000x reference)
//
#include <hip/hip_runtime.h>
#include <math.h>

#define Nn 32
#define Dd 512
#define Pp 4096
#define Kk 64
#define PSEG 4
static constexpr float EPSF = 1e-12f;

// ---------------------------------------------------------------------------
// K2: fused per-pixel norm + 1x1-conv logits + softmax over K
// grid: Nn * (Pp/128) = 1024 blocks, 256 threads
// Per block: one n, 128-pixel tile, all K=64 clusters.
// logits are linear in x, so we accumulate raw dot products and per-pixel
// sum-of-squares in the same D-loop, then scale by 1/norm at the end.
// ---------------------------------------------------------------------------
__global__ __launch_bounds__(256, 2) void k_assign(
    const float* __restrict__ x, const float* __restrict__ w,
    float* __restrict__ a, float* __restrict__ invn, float* __restrict__ asum)
{
  constexpr int PT = 128, DK = 32, LGS = PT + 4;
  __shared__ float xs[DK][PT];      // 16 KB  raw x chunk [d][p]
  __shared__ float wT[DK][Kk];      // 8 KB   w chunk transposed [d][k]
  __shared__ float lg[Kk][LGS];     // 33 KB  logits / a staging (reused for ssq partials)
  __shared__ float invs[PT];

  const int tid = threadIdx.x;
  const int n  = blockIdx.x >> 5;
  const int p0 = (blockIdx.x & 31) * PT;
  const float* xn = x + (size_t)n * Dd * Pp + p0;

  const int tk = tid >> 4, tp = tid & 15;          // GEMM: 4 k's x 8 px (split 4+4)
  const int lr = tid >> 3, lc = (tid & 7) * 16;    // x loader: row, 16-px group
  const int wk = tid >> 2, wd0 = (tid & 3) * 8;    // w loader

  float acc[4][8];
#pragma unroll
  for (int i = 0; i < 4; ++i)
#pragma unroll
    for (int j = 0; j < 8; ++j) acc[i][j] = 0.f;
  float ssq[16];
#pragma unroll
  for (int j = 0; j < 16; ++j) ssq[j] = 0.f;

  for (int dc = 0; dc < Dd; dc += DK) {
    // stage w chunk transposed: wT[dd][k]
    {
      const float* wp = w + (size_t)wk * Dd + dc + wd0;
      float4 w0 = *(const float4*)wp;
      float4 w1 = *(const float4*)(wp + 4);
      wT[wd0 + 0][wk] = w0.x; wT[wd0 + 1][wk] = w0.y;
      wT[wd0 + 2][wk] = w0.z; wT[wd0 + 3][wk] = w0.w;
      wT[wd0 + 4][wk] = w1.x; wT[wd0 + 5][wk] = w1.y;
      wT[wd0 + 6][wk] = w1.z; wT[wd0 + 7][wk] = w1.w;
    }
    // stage x chunk, accumulate per-pixel sum of squares in registers
    {
      const float* xp = xn + (size_t)(dc + lr) * Pp + lc;
#pragma unroll
      for (int j = 0; j < 4; ++j) {
        float4 v = *(const float4*)(xp + j * 4);
        *(float4*)&xs[lr][lc + j * 4] = v;
        ssq[j * 4 + 0] += v.x * v.x; ssq[j * 4 + 1] += v.y * v.y;
        ssq[j * 4 + 2] += v.z * v.z; ssq[j * 4 + 3] += v.w * v.w;
      }
    }
    __syncthreads();
#pragma unroll 8
    for (int d = 0; d < DK; ++d) {
      float4 wv = *(const float4*)&wT[d][tk * 4];
      float xv[8];
      *(float4*)&xv[0] = *(const float4*)&xs[d][tp * 4];
      *(float4*)&xv[4] = *(const float4*)&xs[d][64 + tp * 4];
      float wk4[4] = {wv.x, wv.y, wv.z, wv.w};
#pragma unroll
      for (int i = 0; i < 4; ++i)
#pragma unroll
        for (int j = 0; j < 8; ++j) acc[i][j] += wk4[i] * xv[j];
    }
    __syncthreads();
  }

  // reduce per-pixel sumsq: partials -> lg area (flat, stride PT)
  float* ss = &lg[0][0];
  {
#pragma unroll
    for (int j = 0; j < 4; ++j) {
      float4 v = {ssq[j * 4 + 0], ssq[j * 4 + 1], ssq[j * 4 + 2], ssq[j * 4 + 3]};
      *(float4*)&ss[lr * PT + lc + j * 4] = v;
    }
  }
  __syncthreads();
  if (tid < PT) {
    float s = 0.f;
#pragma unroll
    for (int r = 0; r < DK; ++r) s += ss[r * PT + tid];
    float iv = 1.f / fmaxf(sqrtf(s), EPSF);
    invs[tid] = iv;
    invn[(size_t)n * Pp + p0 + tid] = iv;
  }
  __syncthreads();   // all ss reads done; invs ready

  // scaled logits -> lg
#pragma unroll
  for (int i = 0; i < 4; ++i) {
    int k = tk * 4 + i;
#pragma unroll
    for (int j = 0; j < 8; ++j) {
      int p = (j < 4) ? (tp * 4 + j) : (64 + tp * 4 + (j - 4));
      lg[k][p] = acc[i][j] * invs[p];
    }
  }
  __syncthreads();

  // softmax over K per pixel: 2 threads per pixel (halves of k)
  const int sp = tid & 127, sh = tid >> 7;
  float m = -1e30f;
  for (int k = 0; k < Kk; ++k) m = fmaxf(m, lg[k][sp]);
  float s = 0.f;
  for (int k = 0; k < Kk; ++k) s += __expf(lg[k][sp] - m);
  float sinv = 1.f / s;
  __syncthreads();   // all reads of full column done before halves overwrite
  {
    float* ag = a + ((size_t)n * Kk) * Pp + p0 + sp;
#pragma unroll
    for (int kk = 0; kk < 32; ++kk) {
      int k = sh * 32 + kk;
      float e = __expf(lg[k][sp] - m) * sinv;
      ag[(size_t)k * Pp] = e;
      lg[k][sp] = e;   // own (k,p) only: no race
    }
  }
  __syncthreads();
  // asum[n][k] += sum_p a[k][p]: 4 threads per k
  {
    int k = tid >> 2, pg = tid & 3;
    float s2 = 0.f;
    for (int p = pg; p < PT; p += 4) s2 += lg[k][p];
    s2 += __shfl_down(s2, 2);
    s2 += __shfl_down(s2, 1);
    if (pg == 0) atomicAdd(&asum[n * Kk + k], s2);
  }
}

// ---------------------------------------------------------------------------
// K3: vlad partials: vpart[ps][n][k][d] = sum_{p in seg} a[n,k,p]*x[n,d,p]*inv[n,p]
// grid: Nn * (Dd/128) * PSEG = 512 blocks, 256 threads
// ---------------------------------------------------------------------------
__global__ __launch_bounds__(256, 2) void k_vlad(
    const float* __restrict__ x, const float* __restrict__ a,
    const float* __restrict__ invn, float* __restrict__ vpart)
{
  constexpr int PC = 32, DT = 128, AS = Kk + 4, XS = DT + 4;
  __shared__ float as_[PC][AS];   // a chunk transposed [p][k]
  __shared__ float xs[PC][XS];    // x*inv chunk transposed [p][d]

  const int tid = threadIdx.x;
  const int ps = blockIdx.x & 3;
  const int dt = (blockIdx.x >> 2) & 3;
  const int n  = blockIdx.x >> 4;
  const int d0 = dt * DT;
  const int pb = ps * (Pp / PSEG);

  const int tk = tid >> 4, td = tid & 15;          // 4 k's x 8 d's (split 4+4)
  const int ak = tid >> 2, ap0 = (tid & 3) * 8;    // a loader
  const int xd = tid >> 1, xp0 = (tid & 1) * 16;   // x loader

  float acc[4][8];
#pragma unroll
  for (int i = 0; i < 4; ++i)
#pragma unroll
    for (int j = 0; j < 8; ++j) acc[i][j] = 0.f;

  const float* ivb = invn + (size_t)n * Pp;
  const float* xb  = x + ((size_t)n * Dd + d0 + xd) * Pp;
  const float* ab  = a + ((size_t)n * Kk + ak) * Pp;

  for (int pc = pb; pc < pb + Pp / PSEG; pc += PC) {
    // x chunk * inv, transposed into LDS
    {
      const float* xp = xb + pc + xp0;
      const float* ivp = ivb + pc + xp0;
#pragma unroll
      for (int j = 0; j < 4; ++j) {
        float4 v  = *(const float4*)(xp + j * 4);
        float4 iv = *(const float4*)(ivp + j * 4);
        xs[xp0 + j * 4 + 0][xd] = v.x * iv.x;
        xs[xp0 + j * 4 + 1][xd] = v.y * iv.y;
        xs[xp0 + j * 4 + 2][xd] = v.z * iv.z;
        xs[xp0 + j * 4 + 3][xd] = v.w * iv.w;
      }
    }
    // a chunk transposed into LDS
    {
      const float* apt = ab + pc + ap0;
      float4 a0 = *(const float4*)apt;
      float4 a1 = *(const float4*)(apt + 4);
      as_[ap0 + 0][ak] = a0.x; as_[ap0 + 1][ak] = a0.y;
      as_[ap0 + 2][ak] = a0.z; as_[ap0 + 3][ak] = a0.w;
      as_[ap0 + 4][ak] = a1.x; as_[ap0 + 5][ak] = a1.y;
      as_[ap0 + 6][ak] = a1.z; as_[ap0 + 7][ak] = a1.w;
    }
    __syncthreads();
#pragma unroll 8
    for (int p = 0; p < PC; ++p) {
      float4 av = *(const float4*)&as_[p][tk * 4];
      float xv[8];
      *(float4*)&xv[0] = *(const float4*)&xs[p][td * 4];
      *(float4*)&xv[4] = *(const float4*)&xs[p][64 + td * 4];
      float ak4[4] = {av.x, av.y, av.z, av.w};
#pragma unroll
      for (int i = 0; i < 4; ++i)
#pragma unroll
        for (int j = 0; j < 8; ++j) acc[i][j] += ak4[i] * xv[j];
    }
    __syncthreads();
  }

  float* vp = vpart + (((size_t)ps * Nn + n) * Kk) * Dd + d0;
#pragma unroll
  for (int i = 0; i < 4; ++i) {
    float* row = vp + (size_t)(tk * 4 + i) * Dd;
    float4 v0 = {acc[i][0], acc[i][1], acc[i][2], acc[i][3]};
    float4 v1 = {acc[i][4], acc[i][5], acc[i][6], acc[i][7]};
    *(float4*)&row[td * 4] = v0;
    *(float4*)&row[64 + td * 4] = v1;
  }
}

// ---------------------------------------------------------------------------
// K4: combine partials, subtract asum*centroid, intra-normalize over D,
// accumulate global sumsq per n. grid: Nn*Kk = 2048 blocks, 128 threads
// ---------------------------------------------------------------------------
__global__ __launch_bounds__(128) void k_intra(
    const float* __restrict__ vpart, const float* __restrict__ asum,
    const float* __restrict__ cent, float* __restrict__ out, float* __restrict__ gnsq)
{
  __shared__ float red[2];
  const int nk = blockIdx.x;
  const int n = nk >> 6, k = nk & 63;
  const int tid = threadIdx.x;
  const int d = tid * 4;

  float4 v = {0.f, 0.f, 0.f, 0.f};
#pragma unroll
  for (int ps = 0; ps < PSEG; ++ps) {
    float4 t = *(const float4*)&vpart[(((size_t)ps * Nn + n) * Kk + k) * Dd + d];
    v.x += t.x; v.y += t.y; v.z += t.z; v.w += t.w;
  }
  float s = asum[n * Kk + k];
  float4 c = *(const float4*)&cent[(size_t)k * Dd + d];
  v.x -= s * c.x; v.y -= s * c.y; v.z -= s * c.z; v.w -= s * c.w;

  float q = v.x * v.x + v.y * v.y + v.z * v.z + v.w * v.w;
#pragma unroll
  for (int off = 32; off; off >>= 1) q += __shfl_down(q, off);
  if ((tid & 63) == 0) red[tid >> 6] = q;
  __syncthreads();
  float norm = sqrtf(red[0] + red[1]);
  float r = 1.f / fmaxf(norm, EPSF);
  v.x *= r; v.y *= r; v.z *= r; v.w *= r;
  *(float4*)&out[(size_t)n * (Kk * Dd) + (size_t)k * Dd + d] = v;
  if (tid == 0) {
    float t = norm * r;   // 1 unless degenerate row
    atomicAdd(&gnsq[n], t * t);
  }
}

// ---------------------------------------------------------------------------
// K5: global L2 scale per n (in-place on out)
// ---------------------------------------------------------------------------
__global__ __launch_bounds__(256) void k_gscale(
    float* __restrict__ out, const float* __restrict__ gnsq)
{
  size_t i = ((size_t)blockIdx.x * 256 + threadIdx.x) * 4;
  int n = (int)(i >> 15);   // K*D = 32768 per n
  float r = 1.f / fmaxf(sqrtf(gnsq[n]), EPSF);
  float4 v = *(float4*)&out[i];
  v.x *= r; v.y *= r; v.z *= r; v.w *= r;
  *(float4*)&out[i] = v;
}

extern "C" void kernel_launch(void* const* d_in, const int* in_sizes, int n_in,
                              void* d_out, int out_size, void* d_ws, size_t ws_size,
                              hipStream_t stream) {
  (void)in_sizes; (void)n_in; (void)out_size; (void)ws_size;
  const float* x    = (const float*)d_in[0];   // [N,D,H,W]
  const float* w    = (const float*)d_in[1];   // [K,D]
  const float* cent = (const float*)d_in[2];   // [K,D]
  float* out = (float*)d_out;

  // workspace layout (floats): a[N*K*P] | invn[N*P] | asum[N*K] | gnsq[64 pad] | vpart[PSEG*N*K*D]
  float* ws    = (float*)d_ws;
  float* a     = ws;
  float* invn  = a + (size_t)Nn * Kk * Pp;       // +8,388,608
  float* asum  = invn + (size_t)Nn * Pp;         // +131,072
  float* gnsq  = asum + Nn * Kk;                 // +2,048
  float* vpart = gnsq + 64;                      // +64  -> total ~50.9 MB

  hipMemsetAsync(asum, 0, (Nn * Kk + 64) * sizeof(float), stream);
  k_assign<<<Nn * (Pp / 128), 256, 0, stream>>>(x, w, a, invn, asum);
  k_vlad<<<Nn * 4 * PSEG, 256, 0, stream>>>(x, a, invn, vpart);
  k_intra<<<Nn * Kk, 128, 0, stream>>>(vpart, asum, cent, out, gnsq);
  k_gscale<<<(Nn * Kk * Dd) / (256 * 4), 256, 0, stream>>>(out, gnsq);
}

// Round 2
// 452.139 us; speedup vs baseline: 1.2348x; 1.2348x over previous
//
#include <hip/hip_runtime.h>
#include <hip/hip_bf16.h>
#include <math.h>

#define Nn 32
#define Dd 512
#define Pp 4096
#define Kk 64
#define PSEG 4
static constexpr float EPSF = 1e-12f;

typedef short short8 __attribute__((ext_vector_type(8)));
typedef float floatx4 __attribute__((ext_vector_type(4)));

static __device__ __forceinline__ int f2b2(float a, float b) {
  __hip_bfloat162 h = __float22bfloat162_rn(float2{a, b});
  int r; __builtin_memcpy(&r, &h, 4); return r;
}
static __device__ __forceinline__ short8 pack8(const float* v) {
  union { short8 s; int i[4]; } u;
  u.i[0] = f2b2(v[0], v[1]); u.i[1] = f2b2(v[2], v[3]);
  u.i[2] = f2b2(v[4], v[5]); u.i[3] = f2b2(v[6], v[7]);
  return u.s;
}
static __device__ __forceinline__ short f2b1(float f) {
  unsigned u = __float_as_uint(f);
  return (short)((u + 0x7FFFu + ((u >> 16) & 1u)) >> 16);
}
static __device__ __forceinline__ float b2f(short s) {
  return __uint_as_float(((unsigned)(unsigned short)s) << 16);
}

// ---------------------------------------------------------------------------
// K1: fused norm + 1x1-conv logits (MFMA) + softmax over K
// grid: Nn*32 = 1024 blocks x 256 thr. Block = (n, 128-pixel tile), all K=64.
// Linearity: MFMA raw x (bf16), accumulate ssq alongside, scale logits by
// inv[p] before softmax. Writes a_s = a * inv (bf16) and asum (fp32 atomics).
// ---------------------------------------------------------------------------
__global__ __launch_bounds__(256) void k_assign(
    const float* __restrict__ x, const float* __restrict__ w,
    short* __restrict__ a_s, float* __restrict__ asum)
{
  __shared__ float xs[32][136];   // 17408 B; stride 136 -> B-frag reads 2-way (free)
  __shared__ short wf[2048];      // 4 KB, frag-contiguous w chunk [k][q][8]
  __shared__ float invs[128];

  const int tid = threadIdx.x;
  const int n  = blockIdx.x >> 5;
  const int p0 = (blockIdx.x & 31) * 128;
  const int wave = tid >> 6, lane = tid & 63;
  const int q = lane >> 4, pc = lane & 15;
  const int wp = wave * 32;                   // wave's 32-pixel sub-tile

  const int dr = tid >> 3, fc = tid & 7;      // x loader: row dr, 16-px col group
  const int wk = tid >> 2, wq = tid & 3;      // w loader

  floatx4 acc[4][2];
#pragma unroll
  for (int t = 0; t < 4; ++t)
#pragma unroll
    for (int s = 0; s < 2; ++s) acc[t][s] = floatx4{0.f, 0.f, 0.f, 0.f};
  float s16[16];
#pragma unroll
  for (int e = 0; e < 16; ++e) s16[e] = 0.f;

  const float* xrowb = x + (size_t)n * Dd * Pp + p0 + fc * 16;

  for (int dc = 0; dc < Dd; dc += 32) {
    { // stage w chunk (L2-hot), frag-contiguous bf16
      const float* wr = w + wk * Dd + dc + wq * 8;
      float wv[8];
      *(float4*)&wv[0] = *(const float4*)wr;
      *(float4*)&wv[4] = *(const float4*)(wr + 4);
      *(short8*)&wf[(wk * 4 + wq) * 8] = pack8(wv);
    }
    { // stage x chunk fp32, accumulate per-pixel sumsq
      const float* xr = xrowb + (size_t)(dc + dr) * Pp;
#pragma unroll
      for (int j = 0; j < 4; ++j) {
        float4 v = *(const float4*)(xr + j * 4);
        s16[j * 4 + 0] += v.x * v.x; s16[j * 4 + 1] += v.y * v.y;
        s16[j * 4 + 2] += v.z * v.z; s16[j * 4 + 3] += v.w * v.w;
        *(float4*)&xs[dr][fc * 16 + j * 4] = v;
      }
    }
    __syncthreads();
    short8 af[4];
#pragma unroll
    for (int t = 0; t < 4; ++t)      // A[m=pc][kk=q*8+i] of k-tile t
      af[t] = *(short8*)&wf[((t * 16 + pc) * 4 + q) * 8];
    short8 bf[2];
#pragma unroll
    for (int s = 0; s < 2; ++s) {    // B[kk=q*8+i][n=pc] from fp32 xs, cvt
      float bv[8];
#pragma unroll
      for (int i = 0; i < 8; ++i) bv[i] = xs[q * 8 + i][wp + s * 16 + pc];
      bf[s] = pack8(bv);
    }
#pragma unroll
    for (int t = 0; t < 4; ++t)
#pragma unroll
      for (int s = 0; s < 2; ++s)
        acc[t][s] = __builtin_amdgcn_mfma_f32_16x16x32_bf16(af[t], bf[s], acc[t][s], 0, 0, 0);
    __syncthreads();
  }

  // ---- per-pixel inv norm: reduce 32 partials per pixel ----
  float* ssqp = &xs[0][0];            // reuse xs area (4096 floats)
#pragma unroll
  for (int e = 0; e < 16; ++e) ssqp[e * 256 + tid] = s16[e];
  __syncthreads();
  if (tid < 128) {                    // p = tid; contributors: tid' = d2*8 + (p>>4)
    const int e = tid & 15, f = tid >> 4;
    float s = 0.f;
#pragma unroll
    for (int d2 = 0; d2 < 32; ++d2) s += ssqp[e * 256 + d2 * 8 + f];
    invs[tid] = 1.f / fmaxf(sqrtf(s), EPSF);
  }
  __syncthreads();

  // ---- softmax over K in C-fragment registers (k = t*16 + q*4 + r, p col = pc) ----
  float iv[2] = { invs[wp + pc], invs[wp + 16 + pc] };
  float mx[2] = { -1e30f, -1e30f };
#pragma unroll
  for (int t = 0; t < 4; ++t)
#pragma unroll
    for (int s = 0; s < 2; ++s)
#pragma unroll
      for (int r = 0; r < 4; ++r) {
        float l = acc[t][s][r] * iv[s];
        acc[t][s][r] = l;
        mx[s] = fmaxf(mx[s], l);
      }
#pragma unroll
  for (int s = 0; s < 2; ++s) {
    mx[s] = fmaxf(mx[s], __shfl_xor(mx[s], 16));
    mx[s] = fmaxf(mx[s], __shfl_xor(mx[s], 32));
  }
  float sm[2] = { 0.f, 0.f };
#pragma unroll
  for (int t = 0; t < 4; ++t)
#pragma unroll
    for (int s = 0; s < 2; ++s)
#pragma unroll
      for (int r = 0; r < 4; ++r) {
        float e = __expf(acc[t][s][r] - mx[s]);
        acc[t][s][r] = e;
        sm[s] += e;
      }
#pragma unroll
  for (int s = 0; s < 2; ++s) {
    sm[s] += __shfl_xor(sm[s], 16);
    sm[s] += __shfl_xor(sm[s], 32);
    sm[s] = 1.f / sm[s];
  }

  // stage plain a (bf16) into per-wave LDS region for coalesced transpose-out
  short* ab = (short*)&xs[0][0] + wave * 2048;   // [64 k][32 p-local]
#pragma unroll
  for (int t = 0; t < 4; ++t)
#pragma unroll
    for (int s = 0; s < 2; ++s)
#pragma unroll
      for (int r = 0; r < 4; ++r)
        ab[(t * 16 + q * 4 + r) * 32 + s * 16 + pc] = f2b1(acc[t][s][r] * sm[s]);

  // readout rows: asum partial + a_s = a*inv store (b128)
#pragma unroll
  for (int pass = 0; pass < 4; ++pass) {
    int kr = pass * 16 + (lane >> 2);
    int c8 = (lane & 3) * 8;
    short8 av = *(short8*)&ab[kr * 32 + c8];
    float aw[8]; float s8 = 0.f;
#pragma unroll
    for (int i = 0; i < 8; ++i) { aw[i] = b2f(av[i]); s8 += aw[i]; }
    s8 += __shfl_down(s8, 1);
    s8 += __shfl_down(s8, 2);
    if ((lane & 3) == 0) atomicAdd(&asum[n * Kk + kr], s8);
    float ivv[8];
    *(float4*)&ivv[0] = *(const float4*)&invs[wp + c8];
    *(float4*)&ivv[4] = *(const float4*)&invs[wp + c8 + 4];
    float ov[8];
#pragma unroll
    for (int i = 0; i < 8; ++i) ov[i] = aw[i] * ivv[i];
    *(short8*)(a_s + ((size_t)(n * Kk + kr)) * Pp + p0 + wp + c8) = pack8(ov);
  }
}

// ---------------------------------------------------------------------------
// K2: vlad partials via MFMA, LDS-free. vpart[ps][n][k][d] = sum_{p in seg}
// a_s[n,k,p] * x[n,d,p]. grid: n(32) x dt(4) x ps(4) = 512 blocks x 256 thr.
// A frags: 16B contiguous bf16 from a_s. B frags: 32B fp32 from x, cvt in-reg.
// ---------------------------------------------------------------------------
__global__ __launch_bounds__(256) void k_vlad(
    const float* __restrict__ x, const short* __restrict__ a_s,
    float* __restrict__ vpart)
{
  const int tid = threadIdx.x;
  const int ps = blockIdx.x & 3;
  const int dt = (blockIdx.x >> 2) & 3;
  const int n  = blockIdx.x >> 4;
  const int wave = tid >> 6, lane = tid & 63;
  const int q = lane >> 4, pc = lane & 15;
  const int dw = dt * 128 + wave * 32;
  const int pb = ps * (Pp / PSEG);

  floatx4 acc[4][2];
#pragma unroll
  for (int t = 0; t < 4; ++t)
#pragma unroll
    for (int s = 0; s < 2; ++s) acc[t][s] = floatx4{0.f, 0.f, 0.f, 0.f};

  const short* ab0 = a_s + ((size_t)(n * Kk + pc)) * Pp + q * 8;
  const float* xb0 = x + ((size_t)(n * Dd + dw + pc)) * Pp + q * 8;

#pragma unroll 2
  for (int p = pb; p < pb + Pp / PSEG; p += 32) {
    short8 af[4];
#pragma unroll
    for (int t = 0; t < 4; ++t)
      af[t] = *(const short8*)(ab0 + (size_t)t * 16 * Pp + p);
    short8 bf[2];
#pragma unroll
    for (int s = 0; s < 2; ++s) {
      const float* xp = xb0 + (size_t)s * 16 * Pp + p;
      float bv[8];
      *(float4*)&bv[0] = *(const float4*)xp;
      *(float4*)&bv[4] = *(const float4*)(xp + 4);
      bf[s] = pack8(bv);
    }
#pragma unroll
    for (int t = 0; t < 4; ++t)
#pragma unroll
      for (int s = 0; s < 2; ++s)
        acc[t][s] = __builtin_amdgcn_mfma_f32_16x16x32_bf16(af[t], bf[s], acc[t][s], 0, 0, 0);
  }

  float* vb = vpart + (((size_t)ps * Nn + n) * Kk) * Dd;
#pragma unroll
  for (int t = 0; t < 4; ++t)
#pragma unroll
    for (int s = 0; s < 2; ++s)
#pragma unroll
      for (int r = 0; r < 4; ++r)
        vb[(size_t)(t * 16 + q * 4 + r) * Dd + dw + s * 16 + pc] = acc[t][s][r];
}

// ---------------------------------------------------------------------------
// K3: combine partials, subtract asum*centroid, intra-normalize over D,
// accumulate global sumsq per n. grid: Nn*Kk = 2048 blocks, 128 threads
// ---------------------------------------------------------------------------
__global__ __launch_bounds__(128) void k_intra(
    const float* __restrict__ vpart, const float* __restrict__ asum,
    const float* __restrict__ cent, float* __restrict__ out, float* __restrict__ gnsq)
{
  __shared__ float red[2];
  const int nk = blockIdx.x;
  const int n = nk >> 6, k = nk & 63;
  const int tid = threadIdx.x;
  const int d = tid * 4;

  float4 v = {0.f, 0.f, 0.f, 0.f};
#pragma unroll
  for (int ps = 0; ps < PSEG; ++ps) {
    float4 t = *(const float4*)&vpart[(((size_t)ps * Nn + n) * Kk + k) * Dd + d];
    v.x += t.x; v.y += t.y; v.z += t.z; v.w += t.w;
  }
  float s = asum[n * Kk + k];
  float4 c = *(const float4*)&cent[(size_t)k * Dd + d];
  v.x -= s * c.x; v.y -= s * c.y; v.z -= s * c.z; v.w -= s * c.w;

  float qq = v.x * v.x + v.y * v.y + v.z * v.z + v.w * v.w;
#pragma unroll
  for (int off = 32; off; off >>= 1) qq += __shfl_down(qq, off);
  if ((tid & 63) == 0) red[tid >> 6] = qq;
  __syncthreads();
  float norm = sqrtf(red[0] + red[1]);
  float r = 1.f / fmaxf(norm, EPSF);
  v.x *= r; v.y *= r; v.z *= r; v.w *= r;
  *(float4*)&out[(size_t)n * (Kk * Dd) + (size_t)k * Dd + d] = v;
  if (tid == 0) {
    float t = norm * r;   // 1 unless degenerate row
    atomicAdd(&gnsq[n], t * t);
  }
}

// ---------------------------------------------------------------------------
// K4: global L2 scale per n (in-place on out)
// ---------------------------------------------------------------------------
__global__ __launch_bounds__(256) void k_gscale(
    float* __restrict__ out, const float* __restrict__ gnsq)
{
  size_t i = ((size_t)blockIdx.x * 256 + threadIdx.x) * 4;
  int n = (int)(i >> 15);   // K*D = 32768 per n
  float r = 1.f / fmaxf(sqrtf(gnsq[n]), EPSF);
  float4 v = *(float4*)&out[i];
  v.x *= r; v.y *= r; v.z *= r; v.w *= r;
  *(float4*)&out[i] = v;
}

extern "C" void kernel_launch(void* const* d_in, const int* in_sizes, int n_in,
                              void* d_out, int out_size, void* d_ws, size_t ws_size,
                              hipStream_t stream) {
  (void)in_sizes; (void)n_in; (void)out_size; (void)ws_size;
  const float* x    = (const float*)d_in[0];   // [N,D,H,W]
  const float* w    = (const float*)d_in[1];   // [K,D]
  const float* cent = (const float*)d_in[2];   // [K,D]
  float* out = (float*)d_out;

  // ws layout: a_s bf16 [N*K*P] (16 MB) | asum f32 [2048] | gnsq f32 [64] |
  //            vpart f32 [PSEG*N*K*D] (16 MB)
  short* a_s   = (short*)d_ws;
  float* asum  = (float*)(a_s + (size_t)Nn * Kk * Pp);
  float* gnsq  = asum + Nn * Kk;
  float* vpart = gnsq + 64;

  hipMemsetAsync(asum, 0, (Nn * Kk + 64) * sizeof(float), stream);
  k_assign<<<Nn * 32, 256, 0, stream>>>(x, w, a_s, asum);
  k_vlad<<<Nn * 4 * PSEG, 256, 0, stream>>>(x, a_s, vpart);
  k_intra<<<Nn * Kk, 128, 0, stream>>>(vpart, asum, cent, out, gnsq);
  k_gscale<<<(Nn * Kk * Dd) / (256 * 4), 256, 0, stream>>>(out, gnsq);
}